// Round 5
// baseline (22831.354 us; speedup 1.0000x reference)
//
#include <hip/hip_runtime.h>

#define NPTS 8192
#define DIM  128
// K stored as fp8 e4m3 scaled by S=128:  k8 = 128*exp(-C/0.1)
// recurrences on raw sums r = K8 @ w:    w = (128/8192)/(r + 128e-6)
#define WPREP(x) (0.015625f / ((x) + 1.28e-4f))
#define CONV_TOL 1e-5f

typedef short s16x8 __attribute__((ext_vector_type(8)));
typedef float f32x4 __attribute__((ext_vector_type(4)));
typedef float f32x2 __attribute__((ext_vector_type(2)));

__device__ __forceinline__ ushort f2bf(float f) {
  unsigned u = __float_as_uint(f);
  u += 0x7fffu + ((u >> 16) & 1u);   // RNE
  return (ushort)(u >> 16);
}
__device__ __forceinline__ float bf2f(ushort b) {
  return __uint_as_float(((unsigned)b) << 16);
}

// ---- fp8 e4m3 encode/decode (HW cvt preferred; self-consistent either way)
__device__ __forceinline__ unsigned char fp8_enc_sw(float f) {
  if (f < 0.015625f) {                       // subnormal: step 2^-9
    int mi = (int)rintf(f * 512.0f);
    return (unsigned char)(mi >= 8 ? 0x08 : mi);
  }
  unsigned u = __float_as_uint(f);
  unsigned r = u + 0xfffffu + ((u >> 20) & 1u);  // RNE to 3 mantissa bits
  int e = (int)((r >> 23) & 0xff) - 127;
  unsigned mant = (r >> 20) & 7u;
  if (e > 8 || (e == 8 && mant > 6)) return 0x7e;  // saturate 448
  return (unsigned char)(((e + 7) << 3) | mant);
}
__device__ __forceinline__ float fp8_dec_sw(unsigned b) {
  unsigned E = (b >> 3) & 15u, M = b & 7u;
  float n = __uint_as_float(((E + 120u) << 23) | (M << 20));
  float s = (float)M * 0.001953125f;
  return E ? n : s;
}
__device__ __forceinline__ unsigned char enc1(float f) {
#if __has_builtin(__builtin_amdgcn_cvt_pk_fp8_f32)
  return (unsigned char)(__builtin_amdgcn_cvt_pk_fp8_f32(f, f, 0, false) & 0xff);
#else
  return fp8_enc_sw(f);
#endif
}
template <bool HI>
__device__ __forceinline__ f32x2 dec2(unsigned w) {
#if __has_builtin(__builtin_amdgcn_cvt_pk_f32_fp8)
  return __builtin_amdgcn_cvt_pk_f32_fp8((int)w, HI);
#else
  f32x2 r;
  r.x = fp8_dec_sw(HI ? ((w >> 16) & 0xffu) : (w & 0xffu));
  r.y = fp8_dec_sw(HI ? (w >> 24) : ((w >> 8) & 0xffu));
  return r;
#endif
}

__device__ __forceinline__ int load_nc(const int* p) {
  return __hip_atomic_load(p, __ATOMIC_RELAXED, __HIP_MEMORY_SCOPE_AGENT);
}

// LDS swizzle for the w[] vector (2-way max conflicts for lane*16 strides)
__device__ __forceinline__ int swz(int j) { return j + 2 * (j >> 5); }
#define WSZ (NPTS + 2 * (NPTS / 32) + 8)   // 8712 floats

// ---------------------------------------------------------------- x2 = sum(bf16(x)^2)
__global__ __launch_bounds__(256) void sq_rows(const float* __restrict__ X,
                                               const float* __restrict__ Y,
                                               float* __restrict__ x2,
                                               float* __restrict__ y2) {
  int wave = threadIdx.x >> 6, lane = threadIdx.x & 63;
  int row = blockIdx.x * 4 + wave;               // 0..16383
  const float* src = (row < NPTS) ? X + (size_t)row * DIM
                                  : Y + (size_t)(row - NPTS) * DIM;
  float2 v = *reinterpret_cast<const float2*>(src + lane * 2);
  float ax = bf2f(f2bf(v.x)), ay = bf2f(f2bf(v.y));
  float s = ax * ax + ay * ay;
  for (int off = 32; off; off >>= 1) s += __shfl_down(s, off, 64);
  if (lane == 0) {
    if (row < NPTS) x2[row] = s; else y2[row - NPTS] = s;
  }
}

// ---------------------------------------------------------------- K8 = fp8(128*exp(-10*max(a2+b2-2*A.B^T,0)))
__global__ __launch_bounds__(256) void build_k(const float* __restrict__ A,
                                               const float* __restrict__ B,
                                               const float* __restrict__ a2,
                                               const float* __restrict__ b2,
                                               unsigned char* __restrict__ K8) {
  __shared__ ushort At[128][136];   // +8 pad
  __shared__ ushort Bt[128][136];
  int t = threadIdx.x;
  int tm = blockIdx.x, tn = blockIdx.y;
  {
    int r = t >> 1;
    int c0 = (t & 1) * 64;
    const float* Ar = A + (size_t)(tm * 128 + r) * DIM + c0;
    const float* Br = B + (size_t)(tn * 128 + r) * DIM + c0;
    for (int c = 0; c < 64; c += 4) {
      float4 av = *reinterpret_cast<const float4*>(Ar + c);
      float4 bv = *reinterpret_cast<const float4*>(Br + c);
      unsigned pa0 = (unsigned)f2bf(av.x) | ((unsigned)f2bf(av.y) << 16);
      unsigned pa1 = (unsigned)f2bf(av.z) | ((unsigned)f2bf(av.w) << 16);
      unsigned pb0 = (unsigned)f2bf(bv.x) | ((unsigned)f2bf(bv.y) << 16);
      unsigned pb1 = (unsigned)f2bf(bv.z) | ((unsigned)f2bf(bv.w) << 16);
      *reinterpret_cast<unsigned*>(&At[r][c0 + c + 0]) = pa0;
      *reinterpret_cast<unsigned*>(&At[r][c0 + c + 2]) = pa1;
      *reinterpret_cast<unsigned*>(&Bt[r][c0 + c + 0]) = pb0;
      *reinterpret_cast<unsigned*>(&Bt[r][c0 + c + 2]) = pb1;
    }
  }
  __syncthreads();
  int wave = t >> 6, lane = t & 63;
  int lr = lane & 15;            // A-row / B-col within 16-tile
  int lk = (lane >> 4) * 8;      // k offset
  f32x4 acc[2][8];
  for (int mi = 0; mi < 2; ++mi)
    for (int ni = 0; ni < 8; ++ni)
      acc[mi][ni] = (f32x4){0.f, 0.f, 0.f, 0.f};
  for (int kc = 0; kc < 4; ++kc) {
    s16x8 af[2], bfr[8];
    af[0] = *reinterpret_cast<const s16x8*>(&At[wave * 32 + lr][kc * 32 + lk]);
    af[1] = *reinterpret_cast<const s16x8*>(&At[wave * 32 + 16 + lr][kc * 32 + lk]);
    for (int ni = 0; ni < 8; ++ni)
      bfr[ni] = *reinterpret_cast<const s16x8*>(&Bt[ni * 16 + lr][kc * 32 + lk]);
    for (int mi = 0; mi < 2; ++mi)
      for (int ni = 0; ni < 8; ++ni)
        acc[mi][ni] = __builtin_amdgcn_mfma_f32_16x16x32_bf16(af[mi], bfr[ni],
                                                              acc[mi][ni], 0, 0, 0);
  }
  // D layout: col = lane&15, row = (lane>>4)*4 + reg  [verified m89/m91]
  int drow = (lane >> 4) * 4;
  float a2r[2][4], b2c[8];
  for (int mi = 0; mi < 2; ++mi)
    for (int r = 0; r < 4; ++r) a2r[mi][r] = a2[tm * 128 + wave * 32 + mi * 16 + drow + r];
  for (int ni = 0; ni < 8; ++ni) b2c[ni] = b2[tn * 128 + ni * 16 + lr];
  __syncthreads();  // all LDS frag reads done; reuse At region as byte tile
  unsigned char (*O)[144] = reinterpret_cast<unsigned char (*)[144]>(&At[0][0]);
  for (int mi = 0; mi < 2; ++mi)
    for (int ni = 0; ni < 8; ++ni)
      for (int r = 0; r < 4; ++r) {
        float S = acc[mi][ni][r];
        float C = fmaxf(a2r[mi][r] + b2c[ni] - 2.0f * S, 0.0f);
        // 128*exp(-C/0.1) = 2^(7 - C*10/ln2)
        float kv = exp2f(7.0f - 14.426950408889634f * C);
        O[wave * 32 + mi * 16 + drow + r][ni * 16 + lr] = enc1(kv);
      }
  __syncthreads();
  int row = t >> 1, half = t & 1;
  const uint4* src = reinterpret_cast<const uint4*>(&O[row][half * 64]);
  uint4* dst = reinterpret_cast<uint4*>(K8 + (size_t)(tm * 128 + row) * NPTS + tn * 128 + half * 64);
#pragma unroll
  for (int k = 0; k < 4; ++k) dst[k] = src[k];
}

// ---------------------------------------------------------------- shared row-matvec core (8 rows/block)
__device__ __forceinline__ void prep_w(float* w, const float* __restrict__ in, int init, int t) {
  if (init) {
    for (int j = t; j < NPTS; j += 256) w[swz(j)] = 1.0f;
  } else {
    for (int j = t; j < NPTS; j += 256) w[swz(j)] = WPREP(in[j]);
  }
}

// computes 2 rows/wave; epilogue compares vs old dest values and votes
// non-convergence into nc[chain] (forced for p<=3: dest may be stale/poisoned).
__device__ __forceinline__ void row_block(const unsigned char* __restrict__ K8,
                                          float* __restrict__ out,
                                          int bid, int t, const float* w,
                                          int p, int chain, int* __restrict__ nc) {
  int wave = t >> 6, lane = t & 63;
  int row0 = bid * 8 + wave * 2;
  const unsigned char* K0 = K8 + (size_t)row0 * NPTS;
  const unsigned char* K1 = K0 + NPTS;
  float a0 = 0.f, b0 = 0.f, a1 = 0.f, b1 = 0.f;
  for (int rnd = 0; rnd < 8; ++rnd) {
    int j0 = rnd * 1024 + lane * 16;
    uint4 q0 = *reinterpret_cast<const uint4*>(K0 + j0);
    uint4 q1 = *reinterpret_cast<const uint4*>(K1 + j0);
    const unsigned* p0 = &q0.x;
    const unsigned* p1 = &q1.x;
    int pb = swz(j0);
#pragma unroll
    for (int e = 0; e < 4; ++e) {
      f32x2 w0 = *reinterpret_cast<const f32x2*>(&w[pb + 4 * e]);
      f32x2 w1 = *reinterpret_cast<const f32x2*>(&w[pb + 4 * e + 2]);
      f32x2 k0l = dec2<false>(p0[e]), k0h = dec2<true>(p0[e]);
      f32x2 k1l = dec2<false>(p1[e]), k1h = dec2<true>(p1[e]);
      a0 = fmaf(k0l.x, w0.x, a0); b0 = fmaf(k0l.y, w0.y, b0);
      a0 = fmaf(k0h.x, w1.x, a0); b0 = fmaf(k0h.y, w1.y, b0);
      a1 = fmaf(k1l.x, w0.x, a1); b1 = fmaf(k1l.y, w0.y, b1);
      a1 = fmaf(k1h.x, w1.x, a1); b1 = fmaf(k1h.y, w1.y, b1);
    }
  }
  float s0 = a0 + b0, s1 = a1 + b1;
  for (int off = 32; off; off >>= 1) {
    s0 += __shfl_down(s0, off, 64);
    s1 += __shfl_down(s1, off, 64);
  }
  if (lane == 0) {
    float old0 = out[row0], old1 = out[row0 + 1];
    bool bad = (p <= 3) ||
               !(fabsf(s0 - old0) <= CONV_TOL * fabsf(old0)) ||   // !(...) catches NaN olds
               !(fabsf(s1 - old1) <= CONV_TOL * fabsf(old1));
    if (bad) atomicMax(nc + chain, p);
    out[row0] = s0;
    out[row0 + 1] = s1;
  }
}

// xy row step: also zeroes the buffer the following colpass will atomically fill
__global__ __launch_bounds__(256) void rowpass_xy(const unsigned char* __restrict__ K8,
                                                  const float* __restrict__ in,
                                                  float* __restrict__ out,
                                                  float* __restrict__ vzero,
                                                  int p, int* __restrict__ nc) {
  __shared__ float w[WSZ];
  int t = threadIdx.x;
  if (p > 3 && load_nc(nc + 2) < p - 1) return;   // chain converged: output already in place
  if (t < 8) vzero[blockIdx.x * 8 + t] = 0.0f;
  prep_w(w, in, p == 1, t);
  __syncthreads();
  row_block(K8, out, blockIdx.x, t, w, p, 2, nc);
}

// fused xx/yy step: grid 2048, low half = A-chain (0), high half = B-chain (1)
__global__ __launch_bounds__(256) void rowpass2(const unsigned char* __restrict__ KA,
                                                const unsigned char* __restrict__ KB,
                                                const float* __restrict__ inA,
                                                const float* __restrict__ inB,
                                                float* __restrict__ outA,
                                                float* __restrict__ outB,
                                                int p, int* __restrict__ nc) {
  __shared__ float w[WSZ];
  int t = threadIdx.x;
  int half = blockIdx.x >> 10, bid = blockIdx.x & 1023;
  if (p > 3 && load_nc(nc + half) < p - 1) return;
  const unsigned char* K8 = half ? KB : KA;
  const float* in = half ? inB : inA;
  float* out = half ? outB : outA;
  prep_w(w, in, p == 1, t);
  __syncthreads();
  row_block(K8, out, bid, t, w, p, half, nc);
}

// ---------------------------------------------------------------- vout[j] += sum_i K8[i][j]*u_i (atomic)
__global__ __launch_bounds__(256) void colpass(const unsigned char* __restrict__ K8,
                                               const float* __restrict__ uraw,
                                               float* __restrict__ vout,
                                               int p, int* __restrict__ nc) {
  __shared__ float us[64];
  int t = threadIdx.x;
  if (p > 3 && load_nc(nc + 2) < p - 1) return;   // matches rowpass_xy's decision
  int jb = blockIdx.x;       // 0..7 (1024 cols each)
  int ic = blockIdx.y;       // 0..127 (64 rows each)
  int i0 = ic * 64;
  if (t < 64) us[t] = WPREP(uraw[i0 + t]);
  __syncthreads();
  int j0 = jb * 1024 + t * 4;
  float acc0 = 0.f, acc1 = 0.f, acc2 = 0.f, acc3 = 0.f;
  for (int i = 0; i < 64; i += 4) {
#pragma unroll
    for (int k = 0; k < 4; ++k) {
      unsigned wv = *reinterpret_cast<const unsigned*>(K8 + (size_t)(i0 + i + k) * NPTS + j0);
      float uu = us[i + k];
      f32x2 lo = dec2<false>(wv), hi = dec2<true>(wv);
      acc0 = fmaf(lo.x, uu, acc0);
      acc1 = fmaf(lo.y, uu, acc1);
      acc2 = fmaf(hi.x, uu, acc2);
      acc3 = fmaf(hi.y, uu, acc3);
    }
  }
  atomicAdd(&vout[j0 + 0], acc0);
  atomicAdd(&vout[j0 + 1], acc1);
  atomicAdd(&vout[j0 + 2], acc2);
  atomicAdd(&vout[j0 + 3], acc3);
}

// ---------------------------------------------------------------- partial[wg] = sum_rows u_i * sum_j K*C*v_j
// C = -0.1*ln(k8/128) = 0.0693147*(7 - log2 k8);  K = k8/128 folded into u at the end
__global__ __launch_bounds__(256) void costpass(const unsigned char* __restrict__ K8,
                                                const float* __restrict__ uraw,
                                                const float* __restrict__ vraw,
                                                float* __restrict__ partial) {
  __shared__ float w[WSZ];
  __shared__ float wsum[4];
  int t = threadIdx.x;
  for (int j = t; j < NPTS; j += 256) w[swz(j)] = WPREP(vraw[j]);
  __syncthreads();
  int wave = t >> 6, lane = t & 63;
  int row = blockIdx.x * 4 + wave;
  const unsigned char* Kr = K8 + (size_t)row * NPTS;
  float acc = 0.f;
  for (int rnd = 0; rnd < 8; ++rnd) {
    int j0 = rnd * 1024 + lane * 16;
    uint4 q = *reinterpret_cast<const uint4*>(Kr + j0);
    const unsigned* p = &q.x;
    int pb = swz(j0);
#pragma unroll
    for (int e = 0; e < 4; ++e) {
      f32x2 w0 = *reinterpret_cast<const f32x2*>(&w[pb + 4 * e]);
      f32x2 w1 = *reinterpret_cast<const f32x2*>(&w[pb + 4 * e + 2]);
      f32x2 kl = dec2<false>(p[e]), kh = dec2<true>(p[e]);
      float c0 = (kl.x > 0.f) ? 0.069314718f * (7.0f - __log2f(kl.x)) : 0.f;
      float c1 = (kl.y > 0.f) ? 0.069314718f * (7.0f - __log2f(kl.y)) : 0.f;
      float c2 = (kh.x > 0.f) ? 0.069314718f * (7.0f - __log2f(kh.x)) : 0.f;
      float c3 = (kh.y > 0.f) ? 0.069314718f * (7.0f - __log2f(kh.y)) : 0.f;
      acc = fmaf(kl.x * c0, w0.x, acc);
      acc = fmaf(kl.y * c1, w0.y, acc);
      acc = fmaf(kh.x * c2, w1.x, acc);
      acc = fmaf(kh.y * c3, w1.y, acc);
    }
  }
  for (int off = 32; off; off >>= 1) acc += __shfl_down(acc, off, 64);
  if (lane == 0) {
    float u = WPREP(uraw[row]);
    wsum[wave] = acc * u * 0.0078125f;   // fold K = k8/128
  }
  __syncthreads();
  if (t == 0) partial[blockIdx.x] = (wsum[0] + wsum[1]) + (wsum[2] + wsum[3]);
}

// ---------------------------------------------------------------- div = max(cxy - 0.5*(cxx+cyy), 0)
__global__ __launch_bounds__(256) void final_combine(const float* __restrict__ pxy,
                                                     const float* __restrict__ pxx,
                                                     const float* __restrict__ pyy,
                                                     float* __restrict__ out) {
  __shared__ float buf[3][256];
  int t = threadIdx.x;
  float s0 = 0.f, s1 = 0.f, s2 = 0.f;
  for (int i = t; i < 2048; i += 256) { s0 += pxy[i]; s1 += pxx[i]; s2 += pyy[i]; }
  buf[0][t] = s0; buf[1][t] = s1; buf[2][t] = s2;
  __syncthreads();
  for (int off = 128; off; off >>= 1) {
    if (t < off) {
      buf[0][t] += buf[0][t + off];
      buf[1][t] += buf[1][t + off];
      buf[2][t] += buf[2][t + off];
    }
    __syncthreads();
  }
  if (t == 0) {
    float div = buf[0][0] - 0.5f * (buf[1][0] + buf[2][0]);
    if (!isfinite(div)) div = 0.0f;
    out[0] = fmaxf(div, 0.0f);
  }
}

// ----------------------------------------------------------------
extern "C" void kernel_launch(void* const* d_in, const int* in_sizes, int n_in,
                              void* d_out, int out_size, void* d_ws, size_t ws_size,
                              hipStream_t stream) {
  const float* X = (const float*)d_in[0];
  const float* Y = (const float*)d_in[1];
  float* out = (float*)d_out;
  char* ws = (char*)d_ws;

  size_t off = 0;
  unsigned char* KA = (unsigned char*)(ws + off); off += (size_t)NPTS * NPTS;  // 67 MB
  unsigned char* KB = (unsigned char*)(ws + off); off += (size_t)NPTS * NPTS;  // 67 MB
  float* rxx0 = (float*)(ws + off); off += (size_t)NPTS * 4;
  float* rxx1 = (float*)(ws + off); off += (size_t)NPTS * 4;
  float* ryy0 = (float*)(ws + off); off += (size_t)NPTS * 4;
  float* ryy1 = (float*)(ws + off); off += (size_t)NPTS * 4;
  float* rxy  = (float*)(ws + off); off += (size_t)NPTS * 4;
  float* vab0 = (float*)(ws + off); off += (size_t)NPTS * 4;
  float* vab1 = (float*)(ws + off); off += (size_t)NPTS * 4;
  float* x2   = (float*)(ws + off); off += (size_t)NPTS * 4;
  float* y2   = (float*)(ws + off); off += (size_t)NPTS * 4;
  float* pxy  = (float*)(ws + off); off += 2048 * 4;
  float* pxx  = (float*)(ws + off); off += 2048 * 4;
  float* pyy  = (float*)(ws + off); off += 2048 * 4;
  int*   nc   = (int*)(ws + off);   off += 64;     // notconv[3]: xx, yy, xy
  if (ws_size < off) {
    (void)hipMemsetAsync(d_out, 0, sizeof(float), stream);
    return;
  }
  float* rxx[2] = {rxx0, rxx1};
  float* ryy[2] = {ryy0, ryy1};
  float* vab[2] = {vab0, vab1};

  sq_rows<<<4096, 256, 0, stream>>>(X, Y, x2, y2);

  // ---- XX and YY (symmetric kernels), fused: up to 100 matvec steps each.
  // Early-exit: once r_p == r_{p-2} (rel 1e-5) for all rows, every later pass
  // would rewrite identical values -> blocks return immediately.
  build_k<<<dim3(64, 64), 256, 0, stream>>>(X, X, x2, x2, KA);
  build_k<<<dim3(64, 64), 256, 0, stream>>>(Y, Y, y2, y2, KB);
  for (int p = 1; p <= 100; ++p) {
    rowpass2<<<2048, 256, 0, stream>>>(KA, KB,
                                       rxx[(p - 1) & 1], ryy[(p - 1) & 1],
                                       rxx[p & 1], ryy[p & 1], p, nc);
  }
  // u raw = pass-99-slot ([1]), v raw = pass-100-slot ([0]) (converged values if skipped)
  costpass<<<2048, 256, 0, stream>>>(KA, rxx[1], rxx[0], pxx);
  costpass<<<2048, 256, 0, stream>>>(KB, ryy[1], ryy[0], pyy);

  // ---- XY: up to 50 iterations of rowpass (u) + atomic colpass (v)
  build_k<<<dim3(64, 64), 256, 0, stream>>>(X, Y, x2, y2, KA);
  for (int it = 0; it < 50; ++it) {
    int p = it + 1;
    rowpass_xy<<<1024, 256, 0, stream>>>(KA, vab[it & 1], rxy,
                                         vab[(it + 1) & 1], p, nc);
    colpass<<<dim3(8, 128), 256, 0, stream>>>(KA, rxy, vab[(it + 1) & 1], p, nc);
  }
  costpass<<<2048, 256, 0, stream>>>(KA, rxy, vab[0], pxy);

  final_combine<<<1, 256, 0, stream>>>(pxy, pxx, pyy, out);
}

// Round 6
// 6691.083 us; speedup vs baseline: 3.4122x; 3.4122x over previous
//
#include <hip/hip_runtime.h>

#define NPTS 8192
#define DIM  128
// K stored as fp8 e4m3 scaled by S=128:  k8 = 128*exp(-C/0.1)
// recurrences on raw sums r = K8 @ w:    w = (128/8192)/(r + 128e-6)
#define WPREP(x) (0.015625f / ((x) + 1.28e-4f))
#define CONV_TOL 1e-4f

typedef short s16x8 __attribute__((ext_vector_type(8)));
typedef float f32x4 __attribute__((ext_vector_type(4)));
typedef float f32x2 __attribute__((ext_vector_type(2)));

__device__ __forceinline__ ushort f2bf(float f) {
  unsigned u = __float_as_uint(f);
  u += 0x7fffu + ((u >> 16) & 1u);   // RNE
  return (ushort)(u >> 16);
}
__device__ __forceinline__ float bf2f(ushort b) {
  return __uint_as_float(((unsigned)b) << 16);
}

// ---- fp8 e4m3 encode/decode (HW cvt preferred; self-consistent either way)
__device__ __forceinline__ unsigned char fp8_enc_sw(float f) {
  if (f < 0.015625f) {                       // subnormal: step 2^-9
    int mi = (int)rintf(f * 512.0f);
    return (unsigned char)(mi >= 8 ? 0x08 : mi);
  }
  unsigned u = __float_as_uint(f);
  unsigned r = u + 0xfffffu + ((u >> 20) & 1u);  // RNE to 3 mantissa bits
  int e = (int)((r >> 23) & 0xff) - 127;
  unsigned mant = (r >> 20) & 7u;
  if (e > 8 || (e == 8 && mant > 6)) return 0x7e;  // saturate 448
  return (unsigned char)(((e + 7) << 3) | mant);
}
__device__ __forceinline__ float fp8_dec_sw(unsigned b) {
  unsigned E = (b >> 3) & 15u, M = b & 7u;
  float n = __uint_as_float(((E + 120u) << 23) | (M << 20));
  float s = (float)M * 0.001953125f;
  return E ? n : s;
}
__device__ __forceinline__ unsigned char enc1(float f) {
#if __has_builtin(__builtin_amdgcn_cvt_pk_fp8_f32)
  return (unsigned char)(__builtin_amdgcn_cvt_pk_fp8_f32(f, f, 0, false) & 0xff);
#else
  return fp8_enc_sw(f);
#endif
}
template <bool HI>
__device__ __forceinline__ f32x2 dec2(unsigned w) {
#if __has_builtin(__builtin_amdgcn_cvt_pk_f32_fp8)
  return __builtin_amdgcn_cvt_pk_f32_fp8((int)w, HI);
#else
  f32x2 r;
  r.x = fp8_dec_sw(HI ? ((w >> 16) & 0xffu) : (w & 0xffu));
  r.y = fp8_dec_sw(HI ? (w >> 24) : ((w >> 8) & 0xffu));
  return r;
#endif
}

// LDS swizzle for the w[] vector (2-way max conflicts for lane*16 strides)
__device__ __forceinline__ int swz(int j) { return j + 2 * (j >> 5); }
#define WSZ (NPTS + 2 * (NPTS / 32) + 8)   // 8712 floats

// ---------------------------------------------------------------- nc[3] = 0
__global__ __launch_bounds__(64) void init_nc(int* __restrict__ nc) {
  if (threadIdx.x < 3) nc[threadIdx.x] = 0;
}

// ---------------------------------------------------------------- x2 = sum(bf16(x)^2)
__global__ __launch_bounds__(256) void sq_rows(const float* __restrict__ X,
                                               const float* __restrict__ Y,
                                               float* __restrict__ x2,
                                               float* __restrict__ y2) {
  int wave = threadIdx.x >> 6, lane = threadIdx.x & 63;
  int row = blockIdx.x * 4 + wave;               // 0..16383
  const float* src = (row < NPTS) ? X + (size_t)row * DIM
                                  : Y + (size_t)(row - NPTS) * DIM;
  float2 v = *reinterpret_cast<const float2*>(src + lane * 2);
  float ax = bf2f(f2bf(v.x)), ay = bf2f(f2bf(v.y));
  float s = ax * ax + ay * ay;
  for (int off = 32; off; off >>= 1) s += __shfl_down(s, off, 64);
  if (lane == 0) {
    if (row < NPTS) x2[row] = s; else y2[row - NPTS] = s;
  }
}

// ---------------------------------------------------------------- K8 = fp8(128*exp(-10*max(a2+b2-2*A.B^T,0)))
__global__ __launch_bounds__(256) void build_k(const float* __restrict__ A,
                                               const float* __restrict__ B,
                                               const float* __restrict__ a2,
                                               const float* __restrict__ b2,
                                               unsigned char* __restrict__ K8) {
  __shared__ ushort At[128][136];   // +8 pad
  __shared__ ushort Bt[128][136];
  int t = threadIdx.x;
  int tm = blockIdx.x, tn = blockIdx.y;
  {
    int r = t >> 1;
    int c0 = (t & 1) * 64;
    const float* Ar = A + (size_t)(tm * 128 + r) * DIM + c0;
    const float* Br = B + (size_t)(tn * 128 + r) * DIM + c0;
    for (int c = 0; c < 64; c += 4) {
      float4 av = *reinterpret_cast<const float4*>(Ar + c);
      float4 bv = *reinterpret_cast<const float4*>(Br + c);
      unsigned pa0 = (unsigned)f2bf(av.x) | ((unsigned)f2bf(av.y) << 16);
      unsigned pa1 = (unsigned)f2bf(av.z) | ((unsigned)f2bf(av.w) << 16);
      unsigned pb0 = (unsigned)f2bf(bv.x) | ((unsigned)f2bf(bv.y) << 16);
      unsigned pb1 = (unsigned)f2bf(bv.z) | ((unsigned)f2bf(bv.w) << 16);
      *reinterpret_cast<unsigned*>(&At[r][c0 + c + 0]) = pa0;
      *reinterpret_cast<unsigned*>(&At[r][c0 + c + 2]) = pa1;
      *reinterpret_cast<unsigned*>(&Bt[r][c0 + c + 0]) = pb0;
      *reinterpret_cast<unsigned*>(&Bt[r][c0 + c + 2]) = pb1;
    }
  }
  __syncthreads();
  int wave = t >> 6, lane = t & 63;
  int lr = lane & 15;            // A-row / B-col within 16-tile
  int lk = (lane >> 4) * 8;      // k offset
  f32x4 acc[2][8];
  for (int mi = 0; mi < 2; ++mi)
    for (int ni = 0; ni < 8; ++ni)
      acc[mi][ni] = (f32x4){0.f, 0.f, 0.f, 0.f};
  for (int kc = 0; kc < 4; ++kc) {
    s16x8 af[2], bfr[8];
    af[0] = *reinterpret_cast<const s16x8*>(&At[wave * 32 + lr][kc * 32 + lk]);
    af[1] = *reinterpret_cast<const s16x8*>(&At[wave * 32 + 16 + lr][kc * 32 + lk]);
    for (int ni = 0; ni < 8; ++ni)
      bfr[ni] = *reinterpret_cast<const s16x8*>(&Bt[ni * 16 + lr][kc * 32 + lk]);
    for (int mi = 0; mi < 2; ++mi)
      for (int ni = 0; ni < 8; ++ni)
        acc[mi][ni] = __builtin_amdgcn_mfma_f32_16x16x32_bf16(af[mi], bfr[ni],
                                                              acc[mi][ni], 0, 0, 0);
  }
  // D layout: col = lane&15, row = (lane>>4)*4 + reg  [verified m89/m91]
  int drow = (lane >> 4) * 4;
  float a2r[2][4], b2c[8];
  for (int mi = 0; mi < 2; ++mi)
    for (int r = 0; r < 4; ++r) a2r[mi][r] = a2[tm * 128 + wave * 32 + mi * 16 + drow + r];
  for (int ni = 0; ni < 8; ++ni) b2c[ni] = b2[tn * 128 + ni * 16 + lr];
  __syncthreads();  // all LDS frag reads done; reuse At region as byte tile
  unsigned char (*O)[144] = reinterpret_cast<unsigned char (*)[144]>(&At[0][0]);
  for (int mi = 0; mi < 2; ++mi)
    for (int ni = 0; ni < 8; ++ni)
      for (int r = 0; r < 4; ++r) {
        float S = acc[mi][ni][r];
        float C = fmaxf(a2r[mi][r] + b2c[ni] - 2.0f * S, 0.0f);
        // 128*exp(-C/0.1) = 2^(7 - C*10/ln2)
        float kv = exp2f(7.0f - 14.426950408889634f * C);
        O[wave * 32 + mi * 16 + drow + r][ni * 16 + lr] = enc1(kv);
      }
  __syncthreads();
  int row = t >> 1, half = t & 1;
  const uint4* src = reinterpret_cast<const uint4*>(&O[row][half * 64]);
  uint4* dst = reinterpret_cast<uint4*>(K8 + (size_t)(tm * 128 + row) * NPTS + tn * 128 + half * 64);
#pragma unroll
  for (int k = 0; k < 4; ++k) dst[k] = src[k];
}

// ---------------------------------------------------------------- shared row-matvec core (8 rows/block)
__device__ __forceinline__ void prep_w(float* w, const float* __restrict__ in, int init, int t) {
  if (init) {
    for (int j = t; j < NPTS; j += 256) w[swz(j)] = 1.0f;
  } else {
    for (int j = t; j < NPTS; j += 256) w[swz(j)] = WPREP(in[j]);
  }
}

// computes 2 rows/wave; convergence vote goes into the block-local LDS flag.
__device__ __forceinline__ void row_block(const unsigned char* __restrict__ K8,
                                          float* __restrict__ out,
                                          int bid, int t, const float* w,
                                          int p, int* __restrict__ badf) {
  int wave = t >> 6, lane = t & 63;
  int row0 = bid * 8 + wave * 2;
  const unsigned char* K0 = K8 + (size_t)row0 * NPTS;
  const unsigned char* K1 = K0 + NPTS;
  float a0 = 0.f, b0 = 0.f, a1 = 0.f, b1 = 0.f;
#pragma unroll
  for (int batch = 0; batch < 2; ++batch) {
    uint4 q0[4], q1[4];
#pragma unroll
    for (int r = 0; r < 4; ++r) {
      int j0 = (batch * 4 + r) * 1024 + lane * 16;
      q0[r] = *reinterpret_cast<const uint4*>(K0 + j0);
      q1[r] = *reinterpret_cast<const uint4*>(K1 + j0);
    }
#pragma unroll
    for (int r = 0; r < 4; ++r) {
      int pb = swz((batch * 4 + r) * 1024 + lane * 16);
      const unsigned* p0 = &q0[r].x;
      const unsigned* p1 = &q1[r].x;
#pragma unroll
      for (int e = 0; e < 4; ++e) {
        f32x2 w0 = *reinterpret_cast<const f32x2*>(&w[pb + 4 * e]);
        f32x2 w1 = *reinterpret_cast<const f32x2*>(&w[pb + 4 * e + 2]);
        f32x2 k0l = dec2<false>(p0[e]), k0h = dec2<true>(p0[e]);
        f32x2 k1l = dec2<false>(p1[e]), k1h = dec2<true>(p1[e]);
        a0 = fmaf(k0l.x, w0.x, a0); b0 = fmaf(k0l.y, w0.y, b0);
        a0 = fmaf(k0h.x, w1.x, a0); b0 = fmaf(k0h.y, w1.y, b0);
        a1 = fmaf(k1l.x, w0.x, a1); b1 = fmaf(k1l.y, w0.y, b1);
        a1 = fmaf(k1h.x, w1.x, a1); b1 = fmaf(k1h.y, w1.y, b1);
      }
    }
  }
  float s0 = a0 + b0, s1 = a1 + b1;
  for (int off = 32; off; off >>= 1) {
    s0 += __shfl_down(s0, off, 64);
    s1 += __shfl_down(s1, off, 64);
  }
  if (lane == 0) {
    float old0 = out[row0], old1 = out[row0 + 1];
    bool bad = (p <= 3) ||
               !(fabsf(s0 - old0) <= CONV_TOL * fabsf(old0)) ||   // !(..) catches NaN olds
               !(fabsf(s1 - old1) <= CONV_TOL * fabsf(old1));
    if (bad) atomicOr(badf, 1);          // LDS atomic, cheap
    out[row0] = s0;
    out[row0 + 1] = s1;
  }
}

// xy row step: also zeroes the buffer the following colpass will atomically fill
__global__ __launch_bounds__(256) void rowpass_xy(const unsigned char* __restrict__ K8,
                                                  const float* __restrict__ in,
                                                  float* __restrict__ out,
                                                  float* __restrict__ vzero,
                                                  int p, int* __restrict__ nc) {
  __shared__ float w[WSZ];
  __shared__ int ctl, badf;
  int t = threadIdx.x;
  if (t == 0) { ctl = (p > 3) && (nc[2] < p - 1); badf = 0; }
  __syncthreads();
  if (ctl) return;                       // chain converged: buffers already hold the fixpoint
  if (t < 8) vzero[blockIdx.x * 8 + t] = 0.0f;
  prep_w(w, in, p == 1, t);
  __syncthreads();
  row_block(K8, out, blockIdx.x, t, w, p, &badf);
  __syncthreads();
  if (t == 0 && badf) atomicMax(nc + 2, p);   // one fire-and-forget atomic per block
}

// fused xx/yy step: grid 2048, low half = A-chain (0), high half = B-chain (1)
__global__ __launch_bounds__(256) void rowpass2(const unsigned char* __restrict__ KA,
                                                const unsigned char* __restrict__ KB,
                                                const float* __restrict__ inA,
                                                const float* __restrict__ inB,
                                                float* __restrict__ outA,
                                                float* __restrict__ outB,
                                                int p, int* __restrict__ nc) {
  __shared__ float w[WSZ];
  __shared__ int ctl, badf;
  int t = threadIdx.x;
  int half = blockIdx.x >> 10, bid = blockIdx.x & 1023;
  if (t == 0) { ctl = (p > 3) && (nc[half] < p - 1); badf = 0; }
  __syncthreads();
  if (ctl) return;
  const unsigned char* K8 = half ? KB : KA;
  const float* in = half ? inB : inA;
  float* out = half ? outB : outA;
  prep_w(w, in, p == 1, t);
  __syncthreads();
  row_block(K8, out, bid, t, w, p, &badf);
  __syncthreads();
  if (t == 0 && badf) atomicMax(nc + half, p);
}

// ---------------------------------------------------------------- vout[j] += sum_i K8[i][j]*u_i (atomic)
__global__ __launch_bounds__(256) void colpass(const unsigned char* __restrict__ K8,
                                               const float* __restrict__ uraw,
                                               float* __restrict__ vout,
                                               int p, const int* __restrict__ nc) {
  __shared__ float us[64];
  __shared__ int ctl;
  int t = threadIdx.x;
  if (t == 0) ctl = (p > 3) && (nc[2] < p - 1);   // matches rowpass_xy's decision
  __syncthreads();
  if (ctl) return;
  int jb = blockIdx.x;       // 0..7 (1024 cols each)
  int ic = blockIdx.y;       // 0..127 (64 rows each)
  int i0 = ic * 64;
  if (t < 64) us[t] = WPREP(uraw[i0 + t]);
  __syncthreads();
  int j0 = jb * 1024 + t * 4;
  float acc0 = 0.f, acc1 = 0.f, acc2 = 0.f, acc3 = 0.f;
  for (int i = 0; i < 64; i += 4) {
#pragma unroll
    for (int k = 0; k < 4; ++k) {
      unsigned wv = *reinterpret_cast<const unsigned*>(K8 + (size_t)(i0 + i + k) * NPTS + j0);
      float uu = us[i + k];
      f32x2 lo = dec2<false>(wv), hi = dec2<true>(wv);
      acc0 = fmaf(lo.x, uu, acc0);
      acc1 = fmaf(lo.y, uu, acc1);
      acc2 = fmaf(hi.x, uu, acc2);
      acc3 = fmaf(hi.y, uu, acc3);
    }
  }
  atomicAdd(&vout[j0 + 0], acc0);
  atomicAdd(&vout[j0 + 1], acc1);
  atomicAdd(&vout[j0 + 2], acc2);
  atomicAdd(&vout[j0 + 3], acc3);
}

// ---------------------------------------------------------------- partial[wg] = sum_rows u_i * sum_j K*C*v_j
// C = -0.1*ln(k8/128) = 0.0693147*(7 - log2 k8);  K = k8/128 folded into u at the end
__global__ __launch_bounds__(256) void costpass(const unsigned char* __restrict__ K8,
                                                const float* __restrict__ uraw,
                                                const float* __restrict__ vraw,
                                                float* __restrict__ partial) {
  __shared__ float w[WSZ];
  __shared__ float wsum[4];
  int t = threadIdx.x;
  for (int j = t; j < NPTS; j += 256) w[swz(j)] = WPREP(vraw[j]);
  __syncthreads();
  int wave = t >> 6, lane = t & 63;
  int row = blockIdx.x * 4 + wave;
  const unsigned char* Kr = K8 + (size_t)row * NPTS;
  float acc = 0.f;
  for (int rnd = 0; rnd < 8; ++rnd) {
    int j0 = rnd * 1024 + lane * 16;
    uint4 q = *reinterpret_cast<const uint4*>(Kr + j0);
    const unsigned* p = &q.x;
    int pb = swz(j0);
#pragma unroll
    for (int e = 0; e < 4; ++e) {
      f32x2 w0 = *reinterpret_cast<const f32x2*>(&w[pb + 4 * e]);
      f32x2 w1 = *reinterpret_cast<const f32x2*>(&w[pb + 4 * e + 2]);
      f32x2 kl = dec2<false>(p[e]), kh = dec2<true>(p[e]);
      float c0 = (kl.x > 0.f) ? 0.069314718f * (7.0f - __log2f(kl.x)) : 0.f;
      float c1 = (kl.y > 0.f) ? 0.069314718f * (7.0f - __log2f(kl.y)) : 0.f;
      float c2 = (kh.x > 0.f) ? 0.069314718f * (7.0f - __log2f(kh.x)) : 0.f;
      float c3 = (kh.y > 0.f) ? 0.069314718f * (7.0f - __log2f(kh.y)) : 0.f;
      acc = fmaf(kl.x * c0, w0.x, acc);
      acc = fmaf(kl.y * c1, w0.y, acc);
      acc = fmaf(kh.x * c2, w1.x, acc);
      acc = fmaf(kh.y * c3, w1.y, acc);
    }
  }
  for (int off = 32; off; off >>= 1) acc += __shfl_down(acc, off, 64);
  if (lane == 0) {
    float u = WPREP(uraw[row]);
    wsum[wave] = acc * u * 0.0078125f;   // fold K = k8/128
  }
  __syncthreads();
  if (t == 0) partial[blockIdx.x] = (wsum[0] + wsum[1]) + (wsum[2] + wsum[3]);
}

// ---------------------------------------------------------------- div = max(cxy - 0.5*(cxx+cyy), 0)
__global__ __launch_bounds__(256) void final_combine(const float* __restrict__ pxy,
                                                     const float* __restrict__ pxx,
                                                     const float* __restrict__ pyy,
                                                     float* __restrict__ out) {
  __shared__ float buf[3][256];
  int t = threadIdx.x;
  float s0 = 0.f, s1 = 0.f, s2 = 0.f;
  for (int i = t; i < 2048; i += 256) { s0 += pxy[i]; s1 += pxx[i]; s2 += pyy[i]; }
  buf[0][t] = s0; buf[1][t] = s1; buf[2][t] = s2;
  __syncthreads();
  for (int off = 128; off; off >>= 1) {
    if (t < off) {
      buf[0][t] += buf[0][t + off];
      buf[1][t] += buf[1][t + off];
      buf[2][t] += buf[2][t + off];
    }
    __syncthreads();
  }
  if (t == 0) {
    float div = buf[0][0] - 0.5f * (buf[1][0] + buf[2][0]);
    if (!isfinite(div)) div = 0.0f;
    out[0] = fmaxf(div, 0.0f);
  }
}

// ----------------------------------------------------------------
extern "C" void kernel_launch(void* const* d_in, const int* in_sizes, int n_in,
                              void* d_out, int out_size, void* d_ws, size_t ws_size,
                              hipStream_t stream) {
  const float* X = (const float*)d_in[0];
  const float* Y = (const float*)d_in[1];
  float* out = (float*)d_out;
  char* ws = (char*)d_ws;

  size_t off = 0;
  unsigned char* KA = (unsigned char*)(ws + off); off += (size_t)NPTS * NPTS;  // 67 MB
  unsigned char* KB = (unsigned char*)(ws + off); off += (size_t)NPTS * NPTS;  // 67 MB
  float* rxx0 = (float*)(ws + off); off += (size_t)NPTS * 4;
  float* rxx1 = (float*)(ws + off); off += (size_t)NPTS * 4;
  float* ryy0 = (float*)(ws + off); off += (size_t)NPTS * 4;
  float* ryy1 = (float*)(ws + off); off += (size_t)NPTS * 4;
  float* rxy  = (float*)(ws + off); off += (size_t)NPTS * 4;
  float* vab0 = (float*)(ws + off); off += (size_t)NPTS * 4;
  float* vab1 = (float*)(ws + off); off += (size_t)NPTS * 4;
  float* x2   = (float*)(ws + off); off += (size_t)NPTS * 4;
  float* y2   = (float*)(ws + off); off += (size_t)NPTS * 4;
  float* pxy  = (float*)(ws + off); off += 2048 * 4;
  float* pxx  = (float*)(ws + off); off += 2048 * 4;
  float* pyy  = (float*)(ws + off); off += 2048 * 4;
  int*   nc   = (int*)(ws + off);   off += 64;     // notconv[3]: xx, yy, xy
  if (ws_size < off) {
    (void)hipMemsetAsync(d_out, 0, sizeof(float), stream);
    return;
  }
  float* rxx[2] = {rxx0, rxx1};
  float* ryy[2] = {ryy0, ryy1};
  float* vab[2] = {vab0, vab1};

  init_nc<<<1, 64, 0, stream>>>(nc);
  sq_rows<<<4096, 256, 0, stream>>>(X, Y, x2, y2);

  // ---- XX and YY (symmetric kernels), fused: up to 100 matvec steps each.
  // Early-exit: once r_p == r_{p-2} (rel 1e-4) for all rows, later passes
  // would rewrite identical values -> blocks return immediately.
  build_k<<<dim3(64, 64), 256, 0, stream>>>(X, X, x2, x2, KA);
  build_k<<<dim3(64, 64), 256, 0, stream>>>(Y, Y, y2, y2, KB);
  for (int p = 1; p <= 100; ++p) {
    rowpass2<<<2048, 256, 0, stream>>>(KA, KB,
                                       rxx[(p - 1) & 1], ryy[(p - 1) & 1],
                                       rxx[p & 1], ryy[p & 1], p, nc);
  }
  // u raw = pass-99-slot ([1]), v raw = pass-100-slot ([0]) (converged values if skipped)
  costpass<<<2048, 256, 0, stream>>>(KA, rxx[1], rxx[0], pxx);
  costpass<<<2048, 256, 0, stream>>>(KB, ryy[1], ryy[0], pyy);

  // ---- XY: up to 50 iterations of rowpass (u) + atomic colpass (v)
  build_k<<<dim3(64, 64), 256, 0, stream>>>(X, Y, x2, y2, KA);
  for (int it = 0; it < 50; ++it) {
    int p = it + 1;
    rowpass_xy<<<1024, 256, 0, stream>>>(KA, vab[it & 1], rxy,
                                         vab[(it + 1) & 1], p, nc);
    colpass<<<dim3(8, 128), 256, 0, stream>>>(KA, rxy, vab[(it + 1) & 1], p, nc);
  }
  costpass<<<2048, 256, 0, stream>>>(KA, rxy, vab[0], pxy);

  final_combine<<<1, 256, 0, stream>>>(pxy, pxx, pyy, out);
}

// Round 7
// 5094.404 us; speedup vs baseline: 4.4817x; 1.3134x over previous
//
#include <hip/hip_runtime.h>

#define NPTS 8192
#define DIM  128
// K stored as fp8 e4m3 scaled by S=128:  k8 = 128*exp(-C/0.1)
// recurrences on raw sums r = K8 @ w:    w = (128/8192)/(r + 128e-6)
#define WPREP(x) (0.015625f / ((x) + 1.28e-4f))

typedef short s16x8 __attribute__((ext_vector_type(8)));
typedef float f32x4 __attribute__((ext_vector_type(4)));
typedef float f32x2 __attribute__((ext_vector_type(2)));

__device__ __forceinline__ ushort f2bf(float f) {
  unsigned u = __float_as_uint(f);
  u += 0x7fffu + ((u >> 16) & 1u);   // RNE
  return (ushort)(u >> 16);
}
__device__ __forceinline__ float bf2f(ushort b) {
  return __uint_as_float(((unsigned)b) << 16);
}

// ---- fp8 e4m3 encode/decode (HW cvt preferred; self-consistent either way)
__device__ __forceinline__ unsigned char fp8_enc_sw(float f) {
  if (f < 0.015625f) {                       // subnormal: step 2^-9
    int mi = (int)rintf(f * 512.0f);
    return (unsigned char)(mi >= 8 ? 0x08 : mi);
  }
  unsigned u = __float_as_uint(f);
  unsigned r = u + 0xfffffu + ((u >> 20) & 1u);  // RNE to 3 mantissa bits
  int e = (int)((r >> 23) & 0xff) - 127;
  unsigned mant = (r >> 20) & 7u;
  if (e > 8 || (e == 8 && mant > 6)) return 0x7e;  // saturate 448
  return (unsigned char)(((e + 7) << 3) | mant);
}
__device__ __forceinline__ float fp8_dec_sw(unsigned b) {
  unsigned E = (b >> 3) & 15u, M = b & 7u;
  float n = __uint_as_float(((E + 120u) << 23) | (M << 20));
  float s = (float)M * 0.001953125f;
  return E ? n : s;
}
__device__ __forceinline__ unsigned char enc1(float f) {
#if __has_builtin(__builtin_amdgcn_cvt_pk_fp8_f32)
  return (unsigned char)(__builtin_amdgcn_cvt_pk_fp8_f32(f, f, 0, false) & 0xff);
#else
  return fp8_enc_sw(f);
#endif
}
template <bool HI>
__device__ __forceinline__ f32x2 dec2(unsigned w) {
#if __has_builtin(__builtin_amdgcn_cvt_pk_f32_fp8)
  return __builtin_amdgcn_cvt_pk_f32_fp8((int)w, HI);
#else
  f32x2 r;
  r.x = fp8_dec_sw(HI ? ((w >> 16) & 0xffu) : (w & 0xffu));
  r.y = fp8_dec_sw(HI ? (w >> 24) : ((w >> 8) & 0xffu));
  return r;
#endif
}

// LDS swizzle for the w[] vector (2-way max conflicts for lane*16 strides)
__device__ __forceinline__ int swz(int j) { return j + 2 * (j >> 5); }
#define WSZ (NPTS + 2 * (NPTS / 32) + 8)   // 8712 floats

// ---------------------------------------------------------------- x2 = sum(bf16(x)^2)
__global__ __launch_bounds__(256) void sq_rows(const float* __restrict__ X,
                                               const float* __restrict__ Y,
                                               float* __restrict__ x2,
                                               float* __restrict__ y2) {
  int wave = threadIdx.x >> 6, lane = threadIdx.x & 63;
  int row = blockIdx.x * 4 + wave;               // 0..16383
  const float* src = (row < NPTS) ? X + (size_t)row * DIM
                                  : Y + (size_t)(row - NPTS) * DIM;
  float2 v = *reinterpret_cast<const float2*>(src + lane * 2);
  float ax = bf2f(f2bf(v.x)), ay = bf2f(f2bf(v.y));
  float s = ax * ax + ay * ay;
  for (int off = 32; off; off >>= 1) s += __shfl_down(s, off, 64);
  if (lane == 0) {
    if (row < NPTS) x2[row] = s; else y2[row - NPTS] = s;
  }
}

// ---------------------------------------------------------------- K8 = fp8(128*exp(-10*max(a2+b2-2*A.B^T,0)))
__global__ __launch_bounds__(256) void build_k(const float* __restrict__ A,
                                               const float* __restrict__ B,
                                               const float* __restrict__ a2,
                                               const float* __restrict__ b2,
                                               unsigned char* __restrict__ K8) {
  __shared__ ushort At[128][136];   // +8 pad
  __shared__ ushort Bt[128][136];
  int t = threadIdx.x;
  int tm = blockIdx.x, tn = blockIdx.y;
  {
    int r = t >> 1;
    int c0 = (t & 1) * 64;
    const float* Ar = A + (size_t)(tm * 128 + r) * DIM + c0;
    const float* Br = B + (size_t)(tn * 128 + r) * DIM + c0;
    for (int c = 0; c < 64; c += 4) {
      float4 av = *reinterpret_cast<const float4*>(Ar + c);
      float4 bv = *reinterpret_cast<const float4*>(Br + c);
      unsigned pa0 = (unsigned)f2bf(av.x) | ((unsigned)f2bf(av.y) << 16);
      unsigned pa1 = (unsigned)f2bf(av.z) | ((unsigned)f2bf(av.w) << 16);
      unsigned pb0 = (unsigned)f2bf(bv.x) | ((unsigned)f2bf(bv.y) << 16);
      unsigned pb1 = (unsigned)f2bf(bv.z) | ((unsigned)f2bf(bv.w) << 16);
      *reinterpret_cast<unsigned*>(&At[r][c0 + c + 0]) = pa0;
      *reinterpret_cast<unsigned*>(&At[r][c0 + c + 2]) = pa1;
      *reinterpret_cast<unsigned*>(&Bt[r][c0 + c + 0]) = pb0;
      *reinterpret_cast<unsigned*>(&Bt[r][c0 + c + 2]) = pb1;
    }
  }
  __syncthreads();
  int wave = t >> 6, lane = t & 63;
  int lr = lane & 15;            // A-row / B-col within 16-tile
  int lk = (lane >> 4) * 8;      // k offset
  f32x4 acc[2][8];
  for (int mi = 0; mi < 2; ++mi)
    for (int ni = 0; ni < 8; ++ni)
      acc[mi][ni] = (f32x4){0.f, 0.f, 0.f, 0.f};
  for (int kc = 0; kc < 4; ++kc) {
    s16x8 af[2], bfr[8];
    af[0] = *reinterpret_cast<const s16x8*>(&At[wave * 32 + lr][kc * 32 + lk]);
    af[1] = *reinterpret_cast<const s16x8*>(&At[wave * 32 + 16 + lr][kc * 32 + lk]);
    for (int ni = 0; ni < 8; ++ni)
      bfr[ni] = *reinterpret_cast<const s16x8*>(&Bt[ni * 16 + lr][kc * 32 + lk]);
    for (int mi = 0; mi < 2; ++mi)
      for (int ni = 0; ni < 8; ++ni)
        acc[mi][ni] = __builtin_amdgcn_mfma_f32_16x16x32_bf16(af[mi], bfr[ni],
                                                              acc[mi][ni], 0, 0, 0);
  }
  // D layout: col = lane&15, row = (lane>>4)*4 + reg  [verified m89/m91]
  int drow = (lane >> 4) * 4;
  float a2r[2][4], b2c[8];
  for (int mi = 0; mi < 2; ++mi)
    for (int r = 0; r < 4; ++r) a2r[mi][r] = a2[tm * 128 + wave * 32 + mi * 16 + drow + r];
  for (int ni = 0; ni < 8; ++ni) b2c[ni] = b2[tn * 128 + ni * 16 + lr];
  __syncthreads();  // all LDS frag reads done; reuse At region as byte tile
  unsigned char (*O)[144] = reinterpret_cast<unsigned char (*)[144]>(&At[0][0]);
  for (int mi = 0; mi < 2; ++mi)
    for (int ni = 0; ni < 8; ++ni)
      for (int r = 0; r < 4; ++r) {
        float S = acc[mi][ni][r];
        float C = fmaxf(a2r[mi][r] + b2c[ni] - 2.0f * S, 0.0f);
        // 128*exp(-C/0.1) = 2^(7 - C*10/ln2)
        float kv = exp2f(7.0f - 14.426950408889634f * C);
        O[wave * 32 + mi * 16 + drow + r][ni * 16 + lr] = enc1(kv);
      }
  __syncthreads();
  int row = t >> 1, half = t & 1;
  const uint4* src = reinterpret_cast<const uint4*>(&O[row][half * 64]);
  uint4* dst = reinterpret_cast<uint4*>(K8 + (size_t)(tm * 128 + row) * NPTS + tn * 128 + half * 64);
#pragma unroll
  for (int k = 0; k < 4; ++k) dst[k] = src[k];
}

// ---------------------------------------------------------------- shared row-matvec core
// 512-thread blocks: 8 waves x 2 rows = 16 rows/block, one shared w[] copy.
// LDS 35KB -> 4 blocks/CU -> 32 waves/CU (100% occupancy) for latency hiding.
__device__ __forceinline__ void prep_w(float* w, const float* __restrict__ in, int init, int t) {
  if (init) {
    for (int j = t; j < NPTS; j += 512) w[swz(j)] = 1.0f;
  } else {
    for (int j = t; j < NPTS; j += 512) w[swz(j)] = WPREP(in[j]);
  }
}

__device__ __forceinline__ void row_block(const unsigned char* __restrict__ K8,
                                          float* __restrict__ out,
                                          int row0, int t, const float* w) {
  int lane = t & 63;
  const unsigned char* K0 = K8 + (size_t)row0 * NPTS;
  const unsigned char* K1 = K0 + NPTS;
  float a0 = 0.f, b0 = 0.f, a1 = 0.f, b1 = 0.f;
  for (int rnd = 0; rnd < 8; ++rnd) {
    int j0 = rnd * 1024 + lane * 16;
    uint4 q0 = *reinterpret_cast<const uint4*>(K0 + j0);
    uint4 q1 = *reinterpret_cast<const uint4*>(K1 + j0);
    const unsigned* p0 = &q0.x;
    const unsigned* p1 = &q1.x;
    int pb = swz(j0);
#pragma unroll
    for (int e = 0; e < 4; ++e) {
      f32x2 w0 = *reinterpret_cast<const f32x2*>(&w[pb + 4 * e]);
      f32x2 w1 = *reinterpret_cast<const f32x2*>(&w[pb + 4 * e + 2]);
      f32x2 k0l = dec2<false>(p0[e]), k0h = dec2<true>(p0[e]);
      f32x2 k1l = dec2<false>(p1[e]), k1h = dec2<true>(p1[e]);
      a0 = fmaf(k0l.x, w0.x, a0); b0 = fmaf(k0l.y, w0.y, b0);
      a0 = fmaf(k0h.x, w1.x, a0); b0 = fmaf(k0h.y, w1.y, b0);
      a1 = fmaf(k1l.x, w0.x, a1); b1 = fmaf(k1l.y, w0.y, b1);
      a1 = fmaf(k1h.x, w1.x, a1); b1 = fmaf(k1h.y, w1.y, b1);
    }
  }
  float s0 = a0 + b0, s1 = a1 + b1;
  for (int off = 32; off; off >>= 1) {
    s0 += __shfl_down(s0, off, 64);
    s1 += __shfl_down(s1, off, 64);
  }
  if (lane == 0) { out[row0] = s0; out[row0 + 1] = s1; }
}

// xy row step: also zeroes the buffer the following colpass will atomically fill
__global__ __launch_bounds__(512) void rowpass_xy(const unsigned char* __restrict__ K8,
                                                  const float* __restrict__ in,
                                                  float* __restrict__ out,
                                                  float* __restrict__ vzero,
                                                  int init) {
  __shared__ float w[WSZ];
  int t = threadIdx.x;
  if (t < 16) vzero[blockIdx.x * 16 + t] = 0.0f;
  prep_w(w, in, init, t);
  __syncthreads();
  int row0 = blockIdx.x * 16 + (t >> 6) * 2;
  row_block(K8, out, row0, t, w);
}

// fused xx/yy step: grid 1024, low half = A-chain, high half = B-chain
__global__ __launch_bounds__(512) void rowpass2(const unsigned char* __restrict__ KA,
                                                const unsigned char* __restrict__ KB,
                                                const float* __restrict__ inA,
                                                const float* __restrict__ inB,
                                                float* __restrict__ outA,
                                                float* __restrict__ outB,
                                                int init) {
  __shared__ float w[WSZ];
  int t = threadIdx.x;
  int half = blockIdx.x >> 9, bid = blockIdx.x & 511;
  const unsigned char* K8 = half ? KB : KA;
  const float* in = half ? inB : inA;
  float* out = half ? outB : outA;
  prep_w(w, in, init, t);
  __syncthreads();
  int row0 = bid * 16 + (t >> 6) * 2;
  row_block(K8, out, row0, t, w);
}

// ---------------------------------------------------------------- vout[j] += sum_i K8[i][j]*u_i (atomic)
__global__ __launch_bounds__(256) void colpass(const unsigned char* __restrict__ K8,
                                               const float* __restrict__ uraw,
                                               float* __restrict__ vout) {
  __shared__ float us[64];
  int t = threadIdx.x;
  int jb = blockIdx.x;       // 0..7 (1024 cols each)
  int ic = blockIdx.y;       // 0..127 (64 rows each)
  int i0 = ic * 64;
  if (t < 64) us[t] = WPREP(uraw[i0 + t]);
  __syncthreads();
  int j0 = jb * 1024 + t * 4;
  float acc0 = 0.f, acc1 = 0.f, acc2 = 0.f, acc3 = 0.f;
  for (int i = 0; i < 64; i += 4) {
#pragma unroll
    for (int k = 0; k < 4; ++k) {
      unsigned wv = *reinterpret_cast<const unsigned*>(K8 + (size_t)(i0 + i + k) * NPTS + j0);
      float uu = us[i + k];
      f32x2 lo = dec2<false>(wv), hi = dec2<true>(wv);
      acc0 = fmaf(lo.x, uu, acc0);
      acc1 = fmaf(lo.y, uu, acc1);
      acc2 = fmaf(hi.x, uu, acc2);
      acc3 = fmaf(hi.y, uu, acc3);
    }
  }
  atomicAdd(&vout[j0 + 0], acc0);
  atomicAdd(&vout[j0 + 1], acc1);
  atomicAdd(&vout[j0 + 2], acc2);
  atomicAdd(&vout[j0 + 3], acc3);
}

// ---------------------------------------------------------------- partial[wg] = sum_rows u_i * sum_j K*C*v_j
// C = -0.1*ln(k8/128) = 0.0693147*(7 - log2 k8);  K = k8/128 folded into u at the end
__global__ __launch_bounds__(256) void costpass(const unsigned char* __restrict__ K8,
                                                const float* __restrict__ uraw,
                                                const float* __restrict__ vraw,
                                                float* __restrict__ partial) {
  __shared__ float w[WSZ];
  __shared__ float wsum[4];
  int t = threadIdx.x;
  for (int j = t; j < NPTS; j += 256) w[swz(j)] = WPREP(vraw[j]);
  __syncthreads();
  int wave = t >> 6, lane = t & 63;
  int row = blockIdx.x * 4 + wave;
  const unsigned char* Kr = K8 + (size_t)row * NPTS;
  float acc = 0.f;
  for (int rnd = 0; rnd < 8; ++rnd) {
    int j0 = rnd * 1024 + lane * 16;
    uint4 q = *reinterpret_cast<const uint4*>(Kr + j0);
    const unsigned* p = &q.x;
    int pb = swz(j0);
#pragma unroll
    for (int e = 0; e < 4; ++e) {
      f32x2 w0 = *reinterpret_cast<const f32x2*>(&w[pb + 4 * e]);
      f32x2 w1 = *reinterpret_cast<const f32x2*>(&w[pb + 4 * e + 2]);
      f32x2 kl = dec2<false>(p[e]), kh = dec2<true>(p[e]);
      float c0 = (kl.x > 0.f) ? 0.069314718f * (7.0f - __log2f(kl.x)) : 0.f;
      float c1 = (kl.y > 0.f) ? 0.069314718f * (7.0f - __log2f(kl.y)) : 0.f;
      float c2 = (kh.x > 0.f) ? 0.069314718f * (7.0f - __log2f(kh.x)) : 0.f;
      float c3 = (kh.y > 0.f) ? 0.069314718f * (7.0f - __log2f(kh.y)) : 0.f;
      acc = fmaf(kl.x * c0, w0.x, acc);
      acc = fmaf(kl.y * c1, w0.y, acc);
      acc = fmaf(kh.x * c2, w1.x, acc);
      acc = fmaf(kh.y * c3, w1.y, acc);
    }
  }
  for (int off = 32; off; off >>= 1) acc += __shfl_down(acc, off, 64);
  if (lane == 0) {
    float u = WPREP(uraw[row]);
    wsum[wave] = acc * u * 0.0078125f;   // fold K = k8/128
  }
  __syncthreads();
  if (t == 0) partial[blockIdx.x] = (wsum[0] + wsum[1]) + (wsum[2] + wsum[3]);
}

// ---------------------------------------------------------------- div = max(cxy - 0.5*(cxx+cyy), 0)
__global__ __launch_bounds__(256) void final_combine(const float* __restrict__ pxy,
                                                     const float* __restrict__ pxx,
                                                     const float* __restrict__ pyy,
                                                     float* __restrict__ out) {
  __shared__ float buf[3][256];
  int t = threadIdx.x;
  float s0 = 0.f, s1 = 0.f, s2 = 0.f;
  for (int i = t; i < 2048; i += 256) { s0 += pxy[i]; s1 += pxx[i]; s2 += pyy[i]; }
  buf[0][t] = s0; buf[1][t] = s1; buf[2][t] = s2;
  __syncthreads();
  for (int off = 128; off; off >>= 1) {
    if (t < off) {
      buf[0][t] += buf[0][t + off];
      buf[1][t] += buf[1][t + off];
      buf[2][t] += buf[2][t + off];
    }
    __syncthreads();
  }
  if (t == 0) {
    float div = buf[0][0] - 0.5f * (buf[1][0] + buf[2][0]);
    if (!isfinite(div)) div = 0.0f;
    out[0] = fmaxf(div, 0.0f);
  }
}

// ----------------------------------------------------------------
extern "C" void kernel_launch(void* const* d_in, const int* in_sizes, int n_in,
                              void* d_out, int out_size, void* d_ws, size_t ws_size,
                              hipStream_t stream) {
  const float* X = (const float*)d_in[0];
  const float* Y = (const float*)d_in[1];
  float* out = (float*)d_out;
  char* ws = (char*)d_ws;

  size_t off = 0;
  unsigned char* KA = (unsigned char*)(ws + off); off += (size_t)NPTS * NPTS;  // 67 MB
  unsigned char* KB = (unsigned char*)(ws + off); off += (size_t)NPTS * NPTS;  // 67 MB
  float* rxx0 = (float*)(ws + off); off += (size_t)NPTS * 4;
  float* rxx1 = (float*)(ws + off); off += (size_t)NPTS * 4;
  float* ryy0 = (float*)(ws + off); off += (size_t)NPTS * 4;
  float* ryy1 = (float*)(ws + off); off += (size_t)NPTS * 4;
  float* rxy  = (float*)(ws + off); off += (size_t)NPTS * 4;
  float* vab0 = (float*)(ws + off); off += (size_t)NPTS * 4;
  float* vab1 = (float*)(ws + off); off += (size_t)NPTS * 4;
  float* x2   = (float*)(ws + off); off += (size_t)NPTS * 4;
  float* y2   = (float*)(ws + off); off += (size_t)NPTS * 4;
  float* pxy  = (float*)(ws + off); off += 2048 * 4;
  float* pxx  = (float*)(ws + off); off += 2048 * 4;
  float* pyy  = (float*)(ws + off); off += 2048 * 4;
  if (ws_size < off) {
    (void)hipMemsetAsync(d_out, 0, sizeof(float), stream);
    return;
  }
  float* rxx[2] = {rxx0, rxx1};
  float* ryy[2] = {ryy0, ryy1};
  float* vab[2] = {vab0, vab1};

  sq_rows<<<4096, 256, 0, stream>>>(X, Y, x2, y2);

  // ---- XX and YY (symmetric kernels), fused: 100 matvec steps each
  build_k<<<dim3(64, 64), 256, 0, stream>>>(X, X, x2, x2, KA);
  build_k<<<dim3(64, 64), 256, 0, stream>>>(Y, Y, y2, y2, KB);
  for (int p = 1; p <= 100; ++p) {
    rowpass2<<<1024, 512, 0, stream>>>(KA, KB,
                                       rxx[(p - 1) & 1], ryy[(p - 1) & 1],
                                       rxx[p & 1], ryy[p & 1], p == 1 ? 1 : 0);
  }
  // u raw = pass 99 result (odd -> [1]), v raw = pass 100 result ([0])
  costpass<<<2048, 256, 0, stream>>>(KA, rxx[1], rxx[0], pxx);
  costpass<<<2048, 256, 0, stream>>>(KB, ryy[1], ryy[0], pyy);

  // ---- XY: 50 iterations of rowpass (u) + atomic colpass (v)
  build_k<<<dim3(64, 64), 256, 0, stream>>>(X, Y, x2, y2, KA);
  for (int it = 0; it < 50; ++it) {
    rowpass_xy<<<512, 512, 0, stream>>>(KA, vab[it & 1], rxy,
                                        vab[(it + 1) & 1], it == 0 ? 1 : 0);
    colpass<<<dim3(8, 128), 256, 0, stream>>>(KA, rxy, vab[(it + 1) & 1]);
  }
  costpass<<<2048, 256, 0, stream>>>(KA, rxy, vab[0], pxy);

  final_combine<<<1, 256, 0, stream>>>(pxy, pxx, pyy, out);
}